// Round 13
// baseline (59.413 us; speedup 1.0000x reference)
//
#include <hip/hip_runtime.h>
#include <hip/hip_bf16.h>

#define NN 3072
#define RR 8

typedef float f4 __attribute__((ext_vector_type(4)));

// One pass, disjoint roles (R11 structure), + NONTEMPORAL stores:
// the 302 MB output stream is single-use -> bypass L2 write-allocate.
//   blocks (bx<24, i): default to all (i,j) with batch[j] != batch[i]
//   block  (bx==24, i): entire same-batch range [lo,hi) of row i
__global__ __launch_bounds__(256) void frd_onepass(
    const float* __restrict__ z,       // [N, R]
    const int*   __restrict__ seg,     // [N, N]
    const int*   __restrict__ cls,     // [N]
    const int*   __restrict__ batch,   // [N]
    float*       __restrict__ out)     // [N, N, R]
{
    const int i  = blockIdx.y;
    const int bi = batch[i];                           // uniform -> scalar
    const long long rowout = (long long)i * (NN * RR);
    const int h = threadIdx.x & 1;                     // which half of a pair

    if (blockIdx.x < 24) {
        // ---- FILL role: 24 blocks x 256 threads = 2 threads/pair ----
        const int t = blockIdx.x * 256 + threadIdx.x;  // 0..6143
        const int j = t >> 1;
        const int bj = batch[j];                       // L1/L2-hot 12 KB
        if (bj != bi) {
            f4 v;
            v.x = h ? 0.0f : 1.0f;
            v.y = 0.0f; v.z = 0.0f; v.w = 0.0f;
            __builtin_nontemporal_store(v, (f4*)(out + rowout + (long long)t * 4));
        }
        return;
    }

    // ---- SCATTER role: full coverage of [lo,hi) ----
    // uniform binary search for the row's batch block (L2-hot)
    int l = 0, r = NN;
    while (l < r) { const int m = (l + r) >> 1; if (batch[m] <  bi) l = m + 1; else r = m; }
    const int lo = l;
    r = NN;
    while (l < r) { const int m = (l + r) >> 1; if (batch[m] <= bi) l = m + 1; else r = m; }
    const int hi = l;

    // labels in [0,27): "not in {24,25,26}" <=> (< 24)
    const bool rowok = (cls[i] < 24);
    f4 a = {0.0f, 0.0f, 0.0f, 0.0f};
    if (rowok) a = *(const f4*)(z + i * RR + h * 4);

    f4 dflt;
    dflt.x = h ? 0.0f : 1.0f;
    dflt.y = 0.0f; dflt.z = 0.0f; dflt.w = 0.0f;

    // 2 threads per pair, 128 pairs per iteration, contiguous stores
    for (int p = lo + (threadIdx.x >> 1); p < hi; p += 128) {
        f4 res = dflt;
        if (rowok) {
            // seg_matrix in {0,1}; +eye -> diag never selected: (s==0 && i!=p)
            const int s = seg[(long long)i * NN + p];
            const bool pm = (s == 0) & (i != p) & (cls[p] < 24);
            if (pm) {
                const f4 b = *(const f4*)(z + p * RR + h * 4);
                res = a * b;
            }
        }
        __builtin_nontemporal_store(res, (f4*)(out + rowout + (long long)p * 8 + h * 4));
    }
}

extern "C" void kernel_launch(void* const* d_in, const int* in_sizes, int n_in,
                              void* d_out, int out_size, void* d_ws, size_t ws_size,
                              hipStream_t stream) {
    const float* z     = (const float*)d_in[0];
    const int*   seg   = (const int*)d_in[1];
    const int*   cls   = (const int*)d_in[2];
    const int*   batch = (const int*)d_in[3];
    float* out = (float*)d_out;

    dim3 grid(25, NN);   // 24 fill blocks + 1 scatter block per row
    frd_onepass<<<grid, dim3(256), 0, stream>>>(z, seg, cls, batch, out);
}